// Round 1
// baseline (4843.457 us; speedup 1.0000x reference)
//
#include <hip/hip_runtime.h>
#include <hip/hip_bf16.h>

#define D 64

// Scatter-add: one thread per float4 of x.
// gid -> row = gid/16, col4 = (gid%16)*4.
__global__ void scatter_add_kernel(const float* __restrict__ x,
                                   const int* __restrict__ index,
                                   float* __restrict__ sums,
                                   float* __restrict__ counts,
                                   long long n_vec4) {
    long long gid = (long long)blockIdx.x * blockDim.x + threadIdx.x;
    if (gid >= n_vec4) return;
    long long row = gid >> 4;          // 16 float4 per row (D=64)
    int col4 = (int)(gid & 15) << 2;   // starting column of this float4

    int seg = index[row];              // broadcast among 16 threads of the row
    const float4 v = reinterpret_cast<const float4*>(x)[gid];

    float* dst = sums + (long long)seg * D + col4;
    atomicAdd(dst + 0, v.x);
    atomicAdd(dst + 1, v.y);
    atomicAdd(dst + 2, v.z);
    atomicAdd(dst + 3, v.w);

    if (col4 == 0) {
        atomicAdd(&counts[seg], 1.0f);
    }
}

// out[i] = sums[i] / max(counts[row],1); in-place on d_out, float4-wide.
__global__ void divide_kernel(float* __restrict__ out,
                              const float* __restrict__ counts,
                              long long n_vec4) {
    long long gid = (long long)blockIdx.x * blockDim.x + threadIdx.x;
    if (gid >= n_vec4) return;
    long long row = gid >> 4;
    float c = counts[row];
    float inv = 1.0f / fmaxf(c, 1.0f);
    float4 v = reinterpret_cast<float4*>(out)[gid];
    v.x *= inv; v.y *= inv; v.z *= inv; v.w *= inv;
    reinterpret_cast<float4*>(out)[gid] = v;
}

extern "C" void kernel_launch(void* const* d_in, const int* in_sizes, int n_in,
                              void* d_out, int out_size, void* d_ws, size_t ws_size,
                              hipStream_t stream) {
    const float* x = (const float*)d_in[0];
    const int* index = (const int*)d_in[1];
    // d_in[2] = num_segments (scalar on device); recover host-side from out_size.
    const long long n_rows = in_sizes[1];          // N = 4194304
    const int num_seg = out_size / D;              // 100000

    float* sums = (float*)d_out;                   // accumulate directly into output
    float* counts = (float*)d_ws;                  // num_seg floats of scratch

    // Re-zero every call (harness poisons d_out/d_ws with 0xAA before each launch).
    hipMemsetAsync(d_out, 0, (size_t)out_size * sizeof(float), stream);
    hipMemsetAsync(counts, 0, (size_t)num_seg * sizeof(float), stream);

    const long long n_vec4_in = n_rows * (D / 4);  // 67,108,864
    {
        int block = 256;
        long long grid = (n_vec4_in + block - 1) / block;
        scatter_add_kernel<<<(int)grid, block, 0, stream>>>(x, index, sums, counts, n_vec4_in);
    }

    const long long n_vec4_out = (long long)out_size / 4;
    {
        int block = 256;
        long long grid = (n_vec4_out + block - 1) / block;
        divide_kernel<<<(int)grid, block, 0, stream>>>(sums, counts, n_vec4_out);
    }
}